// Round 6
// baseline (386.658 us; speedup 1.0000x reference)
//
#include <hip/hip_runtime.h>
#include <stdint.h>

#define N_NODES 50000
#define N_EDGES 800000
#define D 512
#define M_PAD 50048    // 391 * 128
#define CAP 64         // bucket slots per node; Poisson(16) overflow ~1e-18
#define CAPSH 6

#define FILL_NB 3125   // 3125*256 = 800000 exact
#define WT_NB   1024   // 1024 blocks: wt row = bid>>1, half-row per block
#define CVT_NB  25024  // 25024*256*4 = M_PAD*D exact
#define GEMM_NB 1564   // 391 * 4 tiles

typedef __attribute__((ext_vector_type(8))) __bf16 bf16x8;
typedef __attribute__((ext_vector_type(4))) float f32x4;

static __device__ __forceinline__ unsigned short f2bf(float f) {
  unsigned u = __float_as_uint(f);
  u += 0x7fff + ((u >> 16) & 1);   // round-to-nearest-even
  return (unsigned short)(u >> 16);
}
static __device__ __forceinline__ float bf2f(unsigned short h) {
  return __uint_as_float(((unsigned)h) << 16);
}

// async global->LDS, 16B per lane; LDS base must be wave-uniform (lane-linear fill)
static __device__ __forceinline__ void gload_lds16(const void* g, void* l) {
  __builtin_amdgcn_global_load_lds((const __attribute__((address_space(1))) unsigned*)g,
                                   (__attribute__((address_space(3))) unsigned*)l, 16, 0, 0);
}

// ---- pre-pass: W transpose-cast + X cast (pure bandwidth) ----
__global__ __launch_bounds__(256) void k_pre(const float* __restrict__ x,
                                             const float* __restrict__ w,
                                             unsigned short* __restrict__ xb,
                                             unsigned short* __restrict__ wt) {
  int bid = blockIdx.x;
  if (bid < WT_NB) {
    int n = bid >> 1;                          // wt row
    int k = ((bid & 1) << 8) + threadIdx.x;    // coalesced write along wt row
    wt[n * D + k] = f2bf(w[k * D + n]);        // strided read; W is 1MB, L2-resident
    return;
  }
  bid -= WT_NB;
  long long base = ((long long)bid * 256 + threadIdx.x) * 4;
  int row = (int)(base >> 9);  // D = 512
  ushort4 o;
  if (row < N_NODES) {
    float4 v = *(const float4*)(x + base);
    o.x = f2bf(v.x); o.y = f2bf(v.y); o.z = f2bf(v.z); o.w = f2bf(v.w);
  } else {
    o.x = 0; o.y = 0; o.z = 0; o.w = 0;
  }
  *(ushort4*)(xb + base) = o;
}

// ---- fused: edge-bucket fill (atomic, latency-bound; rides under GEMM compute)
//      + bf16 GEMM C[M_PAD x D] = A * Bt^T, 128x128 tile, global_load_lds staging,
//        bijective XCD-chunked swizzle so all 4 bn-tiles of a bm-panel share one L2 ----
__global__ __launch_bounds__(256) void k_gf(const unsigned short* __restrict__ A,
                                            const unsigned short* __restrict__ Bt,
                                            unsigned short* __restrict__ C,
                                            const int* __restrict__ esrc,
                                            const int* __restrict__ edst,
                                            const float* __restrict__ ew,
                                            int* __restrict__ cur,
                                            int2* __restrict__ cew) {
  __shared__ unsigned short lds_a[128 * 32];
  __shared__ unsigned short lds_b[128 * 32];

  if (blockIdx.x < FILL_NB) {   // edge-bucket fill blocks launch first, overlap GEMM
    int e = blockIdx.x * 256 + threadIdx.x;   // e < 800000 always (exact)
    int d = edst[e];
    int r = atomicAdd(&cur[d], 1);
    if (r < CAP) cew[(d << CAPSH) + r] = make_int2(esrc[e], __float_as_int(ew[e]));
    return;
  }

  // bijective chunked XCD swizzle (m204): 1564 = 8*195 + 4
  const int orig = blockIdx.x - FILL_NB;
  const int q = GEMM_NB / 8, r = GEMM_NB % 8;
  const int xcd = orig & 7, j = orig >> 3;
  const int wgid = (xcd < r ? xcd * (q + 1) : r * (q + 1) + (xcd - r) * q) + j;
  const int bm = wgid >> 2, bn = wgid & 3;

  const int tid  = threadIdx.x;
  const int m0   = bm * 128, n0 = bn * 128;
  const int wave = tid >> 6, lane = tid & 63;
  const int wm   = wave & 1, wn = wave >> 1;
  const int l15  = lane & 15, quad = lane >> 4;

  f32x4 acc[4][4];
#pragma unroll
  for (int i = 0; i < 4; i++)
#pragma unroll
    for (int jj = 0; jj < 4; jj++) acc[i][jj] = f32x4{0.f, 0.f, 0.f, 0.f};

  for (int kt = 0; kt < D / 32; ++kt) {
    const int k0 = kt * 32;
    __syncthreads();
#pragma unroll
    for (int c = 0; c < 2; c++) {
      int i = c * 256 + wave * 64 + lane;   // 16B chunk id, lane-linear per wave
      int rr = i >> 2, kc = (i & 3) << 3;
      gload_lds16(&A[(long long)(m0 + rr) * D + k0 + kc], &lds_a[(c * 256 + wave * 64) * 8]);
      gload_lds16(&Bt[(long long)(n0 + rr) * D + k0 + kc], &lds_b[(c * 256 + wave * 64) * 8]);
    }
    __syncthreads();
    bf16x8 af[4], bfr[4];
#pragma unroll
    for (int t = 0; t < 4; t++) {
      af[t]  = *(const bf16x8*)&lds_a[(wm * 64 + t * 16 + l15) * 32 + quad * 8];
      bfr[t] = *(const bf16x8*)&lds_b[(wn * 64 + t * 16 + l15) * 32 + quad * 8];
    }
#pragma unroll
    for (int i = 0; i < 4; i++)
#pragma unroll
      for (int jj = 0; jj < 4; jj++)
        acc[i][jj] = __builtin_amdgcn_mfma_f32_16x16x32_bf16(af[i], bfr[jj], acc[i][jj], 0, 0, 0);
  }

#pragma unroll
  for (int i = 0; i < 4; i++)
#pragma unroll
    for (int jj = 0; jj < 4; jj++)
#pragma unroll
      for (int rr = 0; rr < 4; rr++) {
        int row = m0 + wm * 64 + i * 16 + quad * 4 + rr;
        int col = n0 + wn * 64 + jj * 16 + l15;
        C[(long long)row * D + col] = f2bf(acc[i][jj][rr]);
      }
}

// ---- aggregate: one BLOCK per node, bucket CSR (unchanged: 115 µs, pattern-bound) ----
__global__ __launch_bounds__(256) void k_agg(const int* __restrict__ cur,
                                             const int2* __restrict__ cew,
                                             const unsigned short* __restrict__ S,
                                             float* __restrict__ out) {
  __shared__ float s_part[4 * 512];
  const int node  = blockIdx.x;
  int cnt = cur[node];
  cnt = (cnt > CAP) ? CAP : cnt;             // memory-safety clamp (P(overflow)~1e-18)
  const int start = node << CAPSH, end = start + cnt;
  const int wave  = threadIdx.x >> 6, lane = threadIdx.x & 63;
  float a[8];
#pragma unroll
  for (int k = 0; k < 8; k++) a[k] = 0.f;

#define EDGE_FMA(V, W)                                             \
  do {                                                             \
    a[0] = fmaf(W, bf2f((unsigned short)(V.x & 0xffffu)), a[0]);   \
    a[1] = fmaf(W, bf2f((unsigned short)(V.x >> 16)),     a[1]);   \
    a[2] = fmaf(W, bf2f((unsigned short)(V.y & 0xffffu)), a[2]);   \
    a[3] = fmaf(W, bf2f((unsigned short)(V.y >> 16)),     a[3]);   \
    a[4] = fmaf(W, bf2f((unsigned short)(V.z & 0xffffu)), a[4]);   \
    a[5] = fmaf(W, bf2f((unsigned short)(V.z >> 16)),     a[5]);   \
    a[6] = fmaf(W, bf2f((unsigned short)(V.w & 0xffffu)), a[6]);   \
    a[7] = fmaf(W, bf2f((unsigned short)(V.w >> 16)),     a[7]);   \
  } while (0)

#define GATHER(P) (*(const uint4*)(S + (size_t)(P).x * D + lane * 8))

  int e = start + wave;
  // 2-deep pipelined pairs across 4 waves (8 rows in flight per block)
  for (; e + 4 < end; e += 8) {
    int2 p0 = cew[e], p1 = cew[e + 4];
    uint4 v0 = GATHER(p0);
    uint4 v1 = GATHER(p1);
    EDGE_FMA(v0, __int_as_float(p0.y));
    EDGE_FMA(v1, __int_as_float(p1.y));
  }
  if (e < end) {
    int2 p0 = cew[e];
    uint4 v0 = GATHER(p0);
    EDGE_FMA(v0, __int_as_float(p0.y));
  }
#undef GATHER
#undef EDGE_FMA

  // cross-wave combine
  float4* sp = (float4*)&s_part[wave * 512 + lane * 8];
  sp[0] = make_float4(a[0], a[1], a[2], a[3]);
  sp[1] = make_float4(a[4], a[5], a[6], a[7]);
  __syncthreads();
  int col = threadIdx.x * 2;
  float2 r0 = *(const float2*)&s_part[0 * 512 + col];
  float2 r1 = *(const float2*)&s_part[1 * 512 + col];
  float2 r2 = *(const float2*)&s_part[2 * 512 + col];
  float2 r3 = *(const float2*)&s_part[3 * 512 + col];
  float2 res = make_float2(r0.x + r1.x + r2.x + r3.x, r0.y + r1.y + r2.y + r3.y);
  // non-temporal 8B store (out never re-read; keep L2/L3 for S)
  typedef __attribute__((ext_vector_type(2))) float f32x2;
  f32x2 rv = {res.x, res.y};
  __builtin_nontemporal_store(rv, (f32x2*)(out + (size_t)node * D + col));
}

extern "C" void kernel_launch(void* const* d_in, const int* in_sizes, int n_in,
                              void* d_out, int out_size, void* d_ws, size_t ws_size,
                              hipStream_t stream) {
  const float* x    = (const float*)d_in[0];
  const float* w    = (const float*)d_in[1];
  const float* ew   = (const float*)d_in[2];
  const int*   esrc = (const int*)d_in[3];
  const int*   edst = (const int*)d_in[4];
  float* out = (float*)d_out;

  char* p = (char*)d_ws;
  auto align256 = [](size_t v) { return (v + 255) & ~(size_t)255; };
  unsigned short* xb = (unsigned short*)p;  p += align256((size_t)M_PAD * D * 2);
  unsigned short* sb = (unsigned short*)p;  p += align256((size_t)M_PAD * D * 2);
  unsigned short* wt = (unsigned short*)p;  p += align256((size_t)D * D * 2);
  int*   cur  = (int*)p;   p += align256((size_t)N_NODES * 4);
  int2*  cew  = (int2*)p;  p += align256((size_t)N_NODES * CAP * 8);

  // bucket counters must be zero before the fill blocks in k_gf
  hipMemsetAsync(cur, 0, (size_t)N_NODES * 4, stream);
  // pre-pass: W^T cast + X cast (pure bandwidth)
  k_pre<<<WT_NB + CVT_NB, 256, 0, stream>>>(x, w, xb, wt);
  // fused: edge fill (latency) overlapped with GEMM (compute), XCD-chunked tile swizzle
  k_gf<<<FILL_NB + GEMM_NB, 256, 0, stream>>>(xb, wt, sb, esrc, edst, ew, cur, cew);
  // aggregate: one block per node, fixed-capacity bucket CSR
  k_agg<<<N_NODES, 256, 0, stream>>>(cur, cew, sb, out);
}

// Round 9
// 382.314 us; speedup vs baseline: 1.0114x; 1.0114x over previous
//
#include <hip/hip_runtime.h>
#include <stdint.h>

#define N_NODES 50000
#define N_EDGES 800000
#define D 512
#define M_PAD 50048    // 782 * 64
#define CAP 64         // bucket slots per node; Poisson(16) overflow ~1e-18
#define CAPSH 6

// mega-kernel block-role ranges (256 threads each)
#define FILL_NB 3125   // 3125*256 = 800000 exact
#define WT_NB   1024   // 1024 blocks: wt row = bid>>1, half-row per block
#define CVT_NB  25024  // 25024*256*4 = M_PAD*D exact
#define GEMM_NB 782    // M_PAD / 64 row-panels, full N per block

typedef __attribute__((ext_vector_type(8))) __bf16 bf16x8;
typedef __attribute__((ext_vector_type(4))) float f32x4;

static __device__ __forceinline__ unsigned short f2bf(float f) {
  unsigned u = __float_as_uint(f);
  u += 0x7fff + ((u >> 16) & 1);   // round-to-nearest-even
  return (unsigned short)(u >> 16);
}
static __device__ __forceinline__ float bf2f(unsigned short h) {
  return __uint_as_float(((unsigned)h) << 16);
}

// async global->LDS, 16B per lane; LDS base must be wave-uniform (lane-linear fill)
static __device__ __forceinline__ void gload_lds16(const void* g, void* l) {
  __builtin_amdgcn_global_load_lds((const __attribute__((address_space(1))) unsigned*)g,
                                   (__attribute__((address_space(3))) unsigned*)l, 16, 0, 0);
}

// ---- fused: edge-bucket fill (atomic, latency-bound) + W transpose-cast + X cast ----
// fill blocks first so their atomic latency overlaps the bandwidth-bound cvt blocks.
__global__ __launch_bounds__(256) void k_mega(const float* __restrict__ x,
                                              const float* __restrict__ w,
                                              const float* __restrict__ ew,
                                              const int* __restrict__ esrc,
                                              const int* __restrict__ edst,
                                              unsigned short* __restrict__ xb,
                                              unsigned short* __restrict__ wt,
                                              int* __restrict__ cur,
                                              int2* __restrict__ cew) {
  int bid = blockIdx.x;
  if (bid < FILL_NB) {
    int e = bid * 256 + threadIdx.x;   // e < 800000 always (exact grid)
    int d = edst[e];
    int r = atomicAdd(&cur[d], 1);
    if (r < CAP) cew[(d << CAPSH) + r] = make_int2(esrc[e], __float_as_int(ew[e]));
    return;
  }
  bid -= FILL_NB;
  if (bid < WT_NB) {
    int n = bid >> 1;                          // wt row
    int k = ((bid & 1) << 8) + threadIdx.x;    // coalesced write along wt row
    wt[n * D + k] = f2bf(w[k * D + n]);        // strided read; W is 1MB, L2-resident
    return;
  }
  bid -= WT_NB;
  // X cast: fp32 -> bf16, zero-pad rows [N_NODES, M_PAD)
  long long base = ((long long)bid * 256 + threadIdx.x) * 4;
  int row = (int)(base >> 9);  // D = 512
  ushort4 o;
  if (row < N_NODES) {
    float4 v = *(const float4*)(x + base);
    o.x = f2bf(v.x); o.y = f2bf(v.y); o.z = f2bf(v.z); o.w = f2bf(v.w);
  } else {
    o.x = 0; o.y = 0; o.z = 0; o.w = 0;
  }
  *(ushort4*)(xb + base) = o;
}

// ---- bf16 GEMM: C[M_PAD x D] = A * Bt^T.
// One block = 64-row panel x ALL 512 cols -> A read exactly once (51 MB total, was 4x).
// B (0.5 MB) is L2-resident; re-staged per block from L2. 4 waves, wave = 64x128 out.
__global__ __launch_bounds__(256, 2) void k_gemm(const unsigned short* __restrict__ A,
                                                 const unsigned short* __restrict__ Bt,
                                                 unsigned short* __restrict__ C) {
  __shared__ unsigned short lds_a[64 * 32];    // 4 KB
  __shared__ unsigned short lds_b[512 * 32];   // 32 KB
  const int tid  = threadIdx.x;
  const int m0   = blockIdx.x * 64;
  const int wave = tid >> 6, lane = tid & 63;
  const int l15  = lane & 15, quad = lane >> 4;
  const int ncol0 = wave * 128;                // wave's 128-col slice

  f32x4 acc[4][8];
#pragma unroll
  for (int i = 0; i < 4; i++)
#pragma unroll
    for (int j = 0; j < 8; j++) acc[i][j] = f32x4{0.f, 0.f, 0.f, 0.f};

  // staging geometry: chunk = 16B (8 bf16 K-elems); 4 chunks per row of 32 K-elems
  const int ra = tid >> 2, kca = (tid & 3) << 3;   // A: 256 chunks, 1/thread

  for (int kt = 0; kt < D / 32; ++kt) {
    const int k0 = kt * 32;
    __syncthreads();
    // A: 64x32 tile, one 16B chunk per thread
    gload_lds16(&A[(long long)(m0 + ra) * D + k0 + kca], &lds_a[(wave * 64) * 8]);
    // B: 512x32 tile, 8 chunks per thread (from L2)
#pragma unroll
    for (int c = 0; c < 8; c++) {
      int i = c * 256 + wave * 64 + lane;          // lane-linear per wave
      int rb = i >> 2, kcb = (i & 3) << 3;
      gload_lds16(&Bt[(long long)rb * D + k0 + kcb], &lds_b[(c * 256 + wave * 64) * 8]);
    }
    __syncthreads();
    bf16x8 af[4], bfr[8];
#pragma unroll
    for (int t = 0; t < 4; t++)
      af[t] = *(const bf16x8*)&lds_a[(t * 16 + l15) * 32 + quad * 8];
#pragma unroll
    for (int t = 0; t < 8; t++)
      bfr[t] = *(const bf16x8*)&lds_b[(ncol0 + t * 16 + l15) * 32 + quad * 8];
#pragma unroll
    for (int i = 0; i < 4; i++)
#pragma unroll
      for (int j = 0; j < 8; j++)
        acc[i][j] = __builtin_amdgcn_mfma_f32_16x16x32_bf16(af[i], bfr[j], acc[i][j], 0, 0, 0);
  }

#pragma unroll
  for (int i = 0; i < 4; i++)
#pragma unroll
    for (int j = 0; j < 8; j++)
#pragma unroll
      for (int r = 0; r < 4; r++) {
        int row = m0 + i * 16 + quad * 4 + r;
        int col = ncol0 + j * 16 + l15;
        C[(long long)row * D + col] = f2bf(acc[i][j][r]);
      }
}

// ---- aggregate: one BLOCK per node, bucket CSR (pattern-bound at ~115 us) ----
__global__ __launch_bounds__(256) void k_agg(const int* __restrict__ cur,
                                             const int2* __restrict__ cew,
                                             const unsigned short* __restrict__ S,
                                             float* __restrict__ out) {
  __shared__ float s_part[4 * 512];
  const int node  = blockIdx.x;
  int cnt = cur[node];
  cnt = (cnt > CAP) ? CAP : cnt;             // memory-safety clamp (P(overflow)~1e-18)
  const int start = node << CAPSH, end = start + cnt;
  const int wave  = threadIdx.x >> 6, lane = threadIdx.x & 63;
  float a[8];
#pragma unroll
  for (int k = 0; k < 8; k++) a[k] = 0.f;

#define EDGE_FMA(V, W)                                             \
  do {                                                             \
    a[0] = fmaf(W, bf2f((unsigned short)(V.x & 0xffffu)), a[0]);   \
    a[1] = fmaf(W, bf2f((unsigned short)(V.x >> 16)),     a[1]);   \
    a[2] = fmaf(W, bf2f((unsigned short)(V.y & 0xffffu)), a[2]);   \
    a[3] = fmaf(W, bf2f((unsigned short)(V.y >> 16)),     a[3]);   \
    a[4] = fmaf(W, bf2f((unsigned short)(V.z & 0xffffu)), a[4]);   \
    a[5] = fmaf(W, bf2f((unsigned short)(V.z >> 16)),     a[5]);   \
    a[6] = fmaf(W, bf2f((unsigned short)(V.w & 0xffffu)), a[6]);   \
    a[7] = fmaf(W, bf2f((unsigned short)(V.w >> 16)),     a[7]);   \
  } while (0)

#define GATHER(P) (*(const uint4*)(S + (size_t)(P).x * D + lane * 8))

  int e = start + wave;
  // 2-deep pipelined pairs across 4 waves (8 rows in flight per block)
  for (; e + 4 < end; e += 8) {
    int2 p0 = cew[e], p1 = cew[e + 4];
    uint4 v0 = GATHER(p0);
    uint4 v1 = GATHER(p1);
    EDGE_FMA(v0, __int_as_float(p0.y));
    EDGE_FMA(v1, __int_as_float(p1.y));
  }
  if (e < end) {
    int2 p0 = cew[e];
    uint4 v0 = GATHER(p0);
    EDGE_FMA(v0, __int_as_float(p0.y));
  }
#undef GATHER
#undef EDGE_FMA

  // cross-wave combine
  float4* sp = (float4*)&s_part[wave * 512 + lane * 8];
  sp[0] = make_float4(a[0], a[1], a[2], a[3]);
  sp[1] = make_float4(a[4], a[5], a[6], a[7]);
  __syncthreads();
  int col = threadIdx.x * 2;
  float2 r0 = *(const float2*)&s_part[0 * 512 + col];
  float2 r1 = *(const float2*)&s_part[1 * 512 + col];
  float2 r2 = *(const float2*)&s_part[2 * 512 + col];
  float2 r3 = *(const float2*)&s_part[3 * 512 + col];
  float2 res = make_float2(r0.x + r1.x + r2.x + r3.x, r0.y + r1.y + r2.y + r3.y);
  // non-temporal 8B store (out never re-read; keep L2/L3 for S)
  typedef __attribute__((ext_vector_type(2))) float f32x2;
  f32x2 rv = {res.x, res.y};
  __builtin_nontemporal_store(rv, (f32x2*)(out + (size_t)node * D + col));
}

extern "C" void kernel_launch(void* const* d_in, const int* in_sizes, int n_in,
                              void* d_out, int out_size, void* d_ws, size_t ws_size,
                              hipStream_t stream) {
  const float* x    = (const float*)d_in[0];
  const float* w    = (const float*)d_in[1];
  const float* ew   = (const float*)d_in[2];
  const int*   esrc = (const int*)d_in[3];
  const int*   edst = (const int*)d_in[4];
  float* out = (float*)d_out;

  char* p = (char*)d_ws;
  auto align256 = [](size_t v) { return (v + 255) & ~(size_t)255; };
  unsigned short* xb = (unsigned short*)p;  p += align256((size_t)M_PAD * D * 2);
  unsigned short* sb = (unsigned short*)p;  p += align256((size_t)M_PAD * D * 2);
  unsigned short* wt = (unsigned short*)p;  p += align256((size_t)D * D * 2);
  int*   cur  = (int*)p;   p += align256((size_t)N_NODES * 4);
  int2*  cew  = (int2*)p;  p += align256((size_t)N_NODES * CAP * 8);

  // bucket counters must be zero before the fused fill blocks run
  hipMemsetAsync(cur, 0, (size_t)N_NODES * 4, stream);
  // fused: bucket-fill (atomic placement) + W^T cast + X cast   [round-5 structure]
  k_mega<<<FILL_NB + WT_NB + CVT_NB, 256, 0, stream>>>(x, w, ew, esrc, edst, xb, wt, cur, cew);
  // support = X @ W  (bf16 MFMA; 64-row x full-N panels, A read once)
  k_gemm<<<GEMM_NB, 256, 0, stream>>>(xb, wt, sb);
  // aggregate: one block per node, fixed-capacity bucket CSR
  k_agg<<<N_NODES, 256, 0, stream>>>(cur, cew, sb, out);
}

// Round 10
// 368.603 us; speedup vs baseline: 1.0490x; 1.0372x over previous
//
#include <hip/hip_runtime.h>
#include <stdint.h>

#define N_NODES 50000
#define N_EDGES 800000
#define D 512
#define M_PAD 50048    // 391 * 128
#define CAP 64         // bucket slots per node; Poisson(16) overflow ~1e-18
#define CAPSH 6

// mega-kernel block-role ranges (256 threads each)
#define FILL_NB 3125   // 3125*256 = 800000 exact
#define WT_NB   1024   // 1024 blocks: wt row = bid>>1, half-row per block
#define CVT_NB  25024  // 25024*256*4 = M_PAD*D exact
#define GEMM_NB 1564   // 391 * 4 tiles (128x128)

typedef __attribute__((ext_vector_type(8))) __bf16 bf16x8;
typedef __attribute__((ext_vector_type(4))) float f32x4;

static __device__ __forceinline__ unsigned short f2bf(float f) {
  unsigned u = __float_as_uint(f);
  u += 0x7fff + ((u >> 16) & 1);   // round-to-nearest-even
  return (unsigned short)(u >> 16);
}
static __device__ __forceinline__ float bf2f(unsigned short h) {
  return __uint_as_float(((unsigned)h) << 16);
}

// async global->LDS, 16B per lane; LDS base must be wave-uniform (lane-linear fill)
static __device__ __forceinline__ void gload_lds16(const void* g, void* l) {
  __builtin_amdgcn_global_load_lds((const __attribute__((address_space(1))) unsigned*)g,
                                   (__attribute__((address_space(3))) unsigned*)l, 16, 0, 0);
}

// bank-spread swizzle for [row][32-short] LDS tiles: which 16B chunk lives in slot s of row r
static __device__ __forceinline__ int swz4(int r) { return (r + (r >> 2)) & 3; }

// ---- fused: edge-bucket fill (atomic, latency-bound) + W transpose-cast + X cast ----
__global__ __launch_bounds__(256) void k_mega(const float* __restrict__ x,
                                              const float* __restrict__ w,
                                              const float* __restrict__ ew,
                                              const int* __restrict__ esrc,
                                              const int* __restrict__ edst,
                                              unsigned short* __restrict__ xb,
                                              unsigned short* __restrict__ wt,
                                              int* __restrict__ cur,
                                              int2* __restrict__ cew) {
  int bid = blockIdx.x;
  if (bid < FILL_NB) {
    int e = bid * 256 + threadIdx.x;   // e < 800000 always (exact grid)
    int d = edst[e];
    int r = atomicAdd(&cur[d], 1);
    if (r < CAP) cew[(d << CAPSH) + r] = make_int2(esrc[e], __float_as_int(ew[e]));
    return;
  }
  bid -= FILL_NB;
  if (bid < WT_NB) {
    int n = bid >> 1;                          // wt row
    int k = ((bid & 1) << 8) + threadIdx.x;    // coalesced write along wt row
    wt[n * D + k] = f2bf(w[k * D + n]);        // strided read; W is 1MB, L2-resident
    return;
  }
  bid -= WT_NB;
  // X cast: fp32 -> bf16, zero-pad rows [N_NODES, M_PAD)
  long long base = ((long long)bid * 256 + threadIdx.x) * 4;
  int row = (int)(base >> 9);  // D = 512
  ushort4 o;
  if (row < N_NODES) {
    float4 v = *(const float4*)(x + base);
    o.x = f2bf(v.x); o.y = f2bf(v.y); o.z = f2bf(v.z); o.w = f2bf(v.w);
  } else {
    o.x = 0; o.y = 0; o.z = 0; o.w = 0;
  }
  *(ushort4*)(xb + base) = o;
}

// ---- bf16 GEMM: C[M_PAD x D] = A * Bt^T, 128x128 tile, global_load_lds staging.
// (1) LDS chunk-swizzle (pre-swizzled GLOBAL source + swizzled ds_read): kills the
//     ~8-way bank conflict of linear [128][32] reads at 64B row stride.
// (2) bijective XCD-chunked block swizzle: 4 bn-tiles of one bm-panel share an XCD L2
//     -> A panel fetched ~once from HBM instead of 4x.
__global__ __launch_bounds__(256) void k_gemm(const unsigned short* __restrict__ A,
                                              const unsigned short* __restrict__ Bt,
                                              unsigned short* __restrict__ C) {
  __shared__ unsigned short lds_a[128 * 32];
  __shared__ unsigned short lds_b[128 * 32];

  // bijective chunked XCD swizzle (m204): 1564 = 8*195 + 4
  const int orig = blockIdx.x;
  const int q = GEMM_NB / 8, rq = GEMM_NB % 8;
  const int xcd = orig & 7, jj0 = orig >> 3;
  const int wgid = (xcd < rq ? xcd * (q + 1) : rq * (q + 1) + (xcd - rq) * q) + jj0;
  const int bm = wgid >> 2, bn = wgid & 3;

  const int tid  = threadIdx.x;
  const int m0   = bm * 128, n0 = bn * 128;
  const int wave = tid >> 6, lane = tid & 63;
  const int wm   = wave & 1, wn = wave >> 1;
  const int l15  = lane & 15, quad = lane >> 4;

  f32x4 acc[4][4];
#pragma unroll
  for (int i = 0; i < 4; i++)
#pragma unroll
    for (int j = 0; j < 4; j++) acc[i][j] = f32x4{0.f, 0.f, 0.f, 0.f};

  for (int kt = 0; kt < D / 32; ++kt) {
    const int k0 = kt * 32;
    __syncthreads();
#pragma unroll
    for (int c = 0; c < 2; c++) {
      int i = c * 256 + wave * 64 + lane;   // LDS 16B slot id, lane-linear per wave
      int r = i >> 2, s = i & 3;
      int g = s ^ swz4(r);                  // fetch the chunk that belongs in slot s
      gload_lds16(&A[(long long)(m0 + r) * D + k0 + (g << 3)], &lds_a[(c * 256 + wave * 64) * 8]);
      gload_lds16(&Bt[(long long)(n0 + r) * D + k0 + (g << 3)], &lds_b[(c * 256 + wave * 64) * 8]);
    }
    __syncthreads();
    bf16x8 af[4], bfr[4];
#pragma unroll
    for (int t = 0; t < 4; t++) {
      int ra = wm * 64 + t * 16 + l15;
      int rb = wn * 64 + t * 16 + l15;
      af[t]  = *(const bf16x8*)&lds_a[ra * 32 + (quad ^ swz4(ra)) * 8];
      bfr[t] = *(const bf16x8*)&lds_b[rb * 32 + (quad ^ swz4(rb)) * 8];
    }
#pragma unroll
    for (int i = 0; i < 4; i++)
#pragma unroll
      for (int j = 0; j < 4; j++)
        acc[i][j] = __builtin_amdgcn_mfma_f32_16x16x32_bf16(af[i], bfr[j], acc[i][j], 0, 0, 0);
  }

#pragma unroll
  for (int i = 0; i < 4; i++)
#pragma unroll
    for (int j = 0; j < 4; j++)
#pragma unroll
      for (int r = 0; r < 4; r++) {
        int row = m0 + wm * 64 + i * 16 + quad * 4 + r;
        int col = n0 + wn * 64 + j * 16 + l15;
        C[(long long)row * D + col] = f2bf(acc[i][j][r]);
      }
}

// ---- aggregate: one BLOCK per node, bucket CSR (pattern-bound at ~115 us) ----
__global__ __launch_bounds__(256) void k_agg(const int* __restrict__ cur,
                                             const int2* __restrict__ cew,
                                             const unsigned short* __restrict__ S,
                                             float* __restrict__ out) {
  __shared__ float s_part[4 * 512];
  const int node  = blockIdx.x;
  int cnt = cur[node];
  cnt = (cnt > CAP) ? CAP : cnt;             // memory-safety clamp (P(overflow)~1e-18)
  const int start = node << CAPSH, end = start + cnt;
  const int wave  = threadIdx.x >> 6, lane = threadIdx.x & 63;
  float a[8];
#pragma unroll
  for (int k = 0; k < 8; k++) a[k] = 0.f;

#define EDGE_FMA(V, W)                                             \
  do {                                                             \
    a[0] = fmaf(W, bf2f((unsigned short)(V.x & 0xffffu)), a[0]);   \
    a[1] = fmaf(W, bf2f((unsigned short)(V.x >> 16)),     a[1]);   \
    a[2] = fmaf(W, bf2f((unsigned short)(V.y & 0xffffu)), a[2]);   \
    a[3] = fmaf(W, bf2f((unsigned short)(V.y >> 16)),     a[3]);   \
    a[4] = fmaf(W, bf2f((unsigned short)(V.z & 0xffffu)), a[4]);   \
    a[5] = fmaf(W, bf2f((unsigned short)(V.z >> 16)),     a[5]);   \
    a[6] = fmaf(W, bf2f((unsigned short)(V.w & 0xffffu)), a[6]);   \
    a[7] = fmaf(W, bf2f((unsigned short)(V.w >> 16)),     a[7]);   \
  } while (0)

#define GATHER(P) (*(const uint4*)(S + (size_t)(P).x * D + lane * 8))

  int e = start + wave;
  // 2-deep pipelined pairs across 4 waves (8 rows in flight per block)
  for (; e + 4 < end; e += 8) {
    int2 p0 = cew[e], p1 = cew[e + 4];
    uint4 v0 = GATHER(p0);
    uint4 v1 = GATHER(p1);
    EDGE_FMA(v0, __int_as_float(p0.y));
    EDGE_FMA(v1, __int_as_float(p1.y));
  }
  if (e < end) {
    int2 p0 = cew[e];
    uint4 v0 = GATHER(p0);
    EDGE_FMA(v0, __int_as_float(p0.y));
  }
#undef GATHER
#undef EDGE_FMA

  // cross-wave combine
  float4* sp = (float4*)&s_part[wave * 512 + lane * 8];
  sp[0] = make_float4(a[0], a[1], a[2], a[3]);
  sp[1] = make_float4(a[4], a[5], a[6], a[7]);
  __syncthreads();
  int col = threadIdx.x * 2;
  float2 r0 = *(const float2*)&s_part[0 * 512 + col];
  float2 r1 = *(const float2*)&s_part[1 * 512 + col];
  float2 r2 = *(const float2*)&s_part[2 * 512 + col];
  float2 r3 = *(const float2*)&s_part[3 * 512 + col];
  float2 res = make_float2(r0.x + r1.x + r2.x + r3.x, r0.y + r1.y + r2.y + r3.y);
  // non-temporal 8B store (out never re-read; keep L2/L3 for S)
  typedef __attribute__((ext_vector_type(2))) float f32x2;
  f32x2 rv = {res.x, res.y};
  __builtin_nontemporal_store(rv, (f32x2*)(out + (size_t)node * D + col));
}

extern "C" void kernel_launch(void* const* d_in, const int* in_sizes, int n_in,
                              void* d_out, int out_size, void* d_ws, size_t ws_size,
                              hipStream_t stream) {
  const float* x    = (const float*)d_in[0];
  const float* w    = (const float*)d_in[1];
  const float* ew   = (const float*)d_in[2];
  const int*   esrc = (const int*)d_in[3];
  const int*   edst = (const int*)d_in[4];
  float* out = (float*)d_out;

  char* p = (char*)d_ws;
  auto align256 = [](size_t v) { return (v + 255) & ~(size_t)255; };
  unsigned short* xb = (unsigned short*)p;  p += align256((size_t)M_PAD * D * 2);
  unsigned short* sb = (unsigned short*)p;  p += align256((size_t)M_PAD * D * 2);
  unsigned short* wt = (unsigned short*)p;  p += align256((size_t)D * D * 2);
  int*   cur  = (int*)p;   p += align256((size_t)N_NODES * 4);
  int2*  cew  = (int2*)p;  p += align256((size_t)N_NODES * CAP * 8);

  // bucket counters must be zero before the fused fill blocks run
  hipMemsetAsync(cur, 0, (size_t)N_NODES * 4, stream);
  // fused: bucket-fill (atomic placement) + W^T cast + X cast   [round-5 structure]
  k_mega<<<FILL_NB + WT_NB + CVT_NB, 256, 0, stream>>>(x, w, ew, esrc, edst, xb, wt, cur, cew);
  // support = X @ W  (bf16 MFMA; 128x128 tiles, LDS-swizzled reads, XCD-chunked blocks)
  k_gemm<<<GEMM_NB, 256, 0, stream>>>(xb, wt, sb);
  // aggregate: one block per node, fixed-capacity bucket CSR
  k_agg<<<N_NODES, 256, 0, stream>>>(cur, cew, sb, out);
}